// Round 2
// baseline (177.862 us; speedup 1.0000x reference)
//
#include <hip/hip_runtime.h>

// OptimizedLinear: out = x@W^T + bias - lr[:,None]*(x@G^T + bias_grad)
// B=4096, IN=OUT=2048, fp32 in/out. bf16 MFMA fused dual-accumulator GEMM.
//
// Round 9: T3 port — 4-phase-per-K-tile fine interleave (m201 template).
// R8 (counted-vmcnt, coarse 2-phase) was NEUTRAL vs R7 (drain-0): MfmaUtil
// 37.9 both -> barrier drain was never the stall; loads always had ~2500cy
// cover. Remaining gap (2483 cyc/SIMD MFMA floor vs 5400 measured) is the
// coarse read-burst/MFMA-burst lockstep. Per the regime-gate table, T4/T5
// are null on 2-phase and pay only inside the 8-phase schedule, so this
// round installs it: per phase {ds_read subtile; barrier; lgkmcnt(0);
// setprio(1); 16 MFMA; setprio(0); barrier}, 4 phases/K-tile = (j, nt-half).
// Prefetch: 8-load burst for tile t+1 in tile t's phase 0 (buf t+1&1 is
// dead since tile t-1's last lgkmcnt+barrier); vmcnt(0) at tile end is a
// no-op-in-time (3.5 phases of cover). Numerics: per-accumulator update
// order unchanged -> absmax must stay 0.03125.
//
// Lessons carried: granule-XOR layout conflict-free (R2-R8, SQ_LDS_BANK_
// CONFLICT=0); per-wave scattered A-loads poison drains (R6); 256-reg acc
// spills (R5 tripwire: WRITE_SIZE >> 45MB); occupancy not the lever (R4);
// counted-vmcnt alone null (R8); XCD swizzle neutral here (L3-resident)
// but kept (harmless, helps if HBM-bound shapes appear).

typedef unsigned short ushort_t;
typedef __attribute__((ext_vector_type(8))) short short8;       // 8 bf16 = 4 VGPR
typedef __attribute__((ext_vector_type(8))) unsigned short ushort8;
typedef __attribute__((ext_vector_type(4))) float f32x4;

#define GPTR(p) ((const __attribute__((address_space(1))) void*)(p))
#define LPTR(p) ((__attribute__((address_space(3))) void*)(p))

static constexpr int Kdim = 2048;
static constexpr int Ndim = 2048;
static constexpr int BK   = 64;
static constexpr int BM   = 256;
static constexpr int BN   = 128;
static constexpr int NT   = Kdim / BK;   // 32 K-tiles

__device__ __forceinline__ unsigned short f2bf(float f) {
    union { float f; unsigned u; } c; c.f = f;
    unsigned u = c.u;
    unsigned r = (u + 0x7fffu + ((u >> 16) & 1u)) >> 16;  // RNE
    return (unsigned short)r;
}

// One launch converts x (uX ushort8-units), W (uW), G (uW). Unit = 8 elems.
__global__ void cvt_all_kernel(const float* __restrict__ x,
                               const float* __restrict__ W,
                               const float* __restrict__ G,
                               ushort_t* __restrict__ xb,
                               ushort_t* __restrict__ wb,
                               ushort_t* __restrict__ gb,
                               int uX, int uW) {
    int u = blockIdx.x * blockDim.x + threadIdx.x;
    const float* src; ushort_t* dst;
    if (u < uX)            { src = x; dst = xb; }
    else if (u < uX + uW)  { src = W; dst = wb; u -= uX; }
    else                   { src = G; dst = gb; u -= uX + uW; }
    int i = u * 8;
    float4 a = *(const float4*)(src + i);
    float4 b = *(const float4*)(src + i + 4);
    ushort8 r;
    r[0] = f2bf(a.x); r[1] = f2bf(a.y); r[2] = f2bf(a.z); r[3] = f2bf(a.w);
    r[4] = f2bf(b.x); r[5] = f2bf(b.y); r[6] = f2bf(b.z); r[7] = f2bf(b.w);
    *(ushort8*)(dst + i) = r;
}

// ---- fused dual GEMM, 256x128 block tile, BK=64, 8 waves, 4-phase ----
// 512 threads = 8 waves (4 M x 2 N), each wave 64x64 = 4x4 MFMA tiles, dual
// acc. LDS: A 256x64, W/G 128x64 bf16, double-buffered: 128 KB (1 block/CU).
// Granule (row r, g=k/8) lives at slot r*8 + (g ^ (r&7)); swizzle applied on
// the GLOBAL fetch address (LDS dst is HW-forced to base + lane*16).
// Fragment read: addr = row*64 + ((j*4+quad) ^ (row&7))*8 -> conflict-free
// (measured 0 bank conflicts across R2-R8 with the identical layout).
__global__ __launch_bounds__(512, 2) void fused_gemm_kernel(
    const ushort_t* __restrict__ xb,   // [4096, 2048] bf16
    const ushort_t* __restrict__ wb,   // [2048, 2048] bf16
    const ushort_t* __restrict__ gb,   // [2048, 2048] bf16
    const float* __restrict__ bias,    // [2048]
    const float* __restrict__ bgrad,   // [2048]
    const float* __restrict__ lr,      // [4096]
    float* __restrict__ out)           // [4096, 2048] fp32
{
    __shared__ ushort_t As[2][BM * BK];  // 2 x 32 KB
    __shared__ ushort_t Ws[2][BN * BK];  // 2 x 16 KB
    __shared__ ushort_t Gs[2][BN * BK];  // 2 x 16 KB

    const int t    = threadIdx.x;
    const int wave = t >> 6;
    const int lane = t & 63;
    const int wm   = (wave >> 1) * 64;   // 0,64,128,192
    const int wn   = (wave & 1) * 64;    // 0,64

    // XCD-chunked swizzle: 256 blocks, 8 XCDs, 32 blocks/XCD = 2 by-rows x 16 bx.
    const int bid = blockIdx.y * 16 + blockIdx.x;
    const int swz = (bid & 7) * 32 + (bid >> 3);
    const int by  = swz >> 4;   // M tile (0..15)
    const int bx  = swz & 15;   // N tile (0..15)

    const int fr   = lane & 15;    // fragment row
    const int quad = lane >> 4;    // k-granule select (0..3)

    f32x4 accB[4][4] = {};
    f32x4 accP[4][4] = {};

    // --- staging addressing ---
    // A: 2048 slots of 16B (4 issues/thread). W/G: 1024 slots (2 issues each).
    // slot s: row = s>>3, fetched granule q' = (s&7) ^ (row&7)
    const ushort_t* gA[4]; int dA[4];
#pragma unroll
    for (int i = 0; i < 4; ++i) {
        int s   = i * 512 + t;
        int row = s >> 3;
        int q   = ((s & 7) ^ (row & 7)) * 8;
        gA[i] = xb + (size_t)(by * BM + row) * Kdim + q;
        dA[i] = (i * 512 + wave * 64) * 8;   // wave-uniform base; HW adds lane*16B
    }
    const ushort_t* gW[2]; const ushort_t* gG[2]; int dW[2];
#pragma unroll
    for (int i = 0; i < 2; ++i) {
        int s   = i * 512 + t;
        int row = s >> 3;
        int q   = ((s & 7) ^ (row & 7)) * 8;
        gW[i] = wb + (size_t)(bx * BN + row) * Kdim + q;
        gG[i] = gb + (size_t)(bx * BN + row) * Kdim + q;
        dW[i] = (i * 512 + wave * 64) * 8;
    }

    short8 af[4], wf[4], gf[4];

    // 8 global_load_lds per thread per K-tile (4 A + 2 W + 2 G)
#define STAGE(B, K0) do {                                                         \
    _Pragma("unroll")                                                             \
    for (int i = 0; i < 4; ++i)                                                   \
        __builtin_amdgcn_global_load_lds(GPTR(gA[i] + (K0)),                      \
                                         LPTR(&As[B][dA[i]]), 16, 0, 0);          \
    _Pragma("unroll")                                                             \
    for (int i = 0; i < 2; ++i) {                                                 \
        __builtin_amdgcn_global_load_lds(GPTR(gW[i] + (K0)),                      \
                                         LPTR(&Ws[B][dW[i]]), 16, 0, 0);          \
        __builtin_amdgcn_global_load_lds(GPTR(gG[i] + (K0)),                      \
                                         LPTR(&Gs[B][dW[i]]), 16, 0, 0);          \
    }                                                                             \
} while (0)

    // fragment reads; kc identical to R7/R8 ((row&7)==(fr&7) since wm,mt*16
    // are multiples of 8)
#define RD_A(B, J) do {                                                           \
    const int kc_ = (((J) * 4 + quad) ^ (fr & 7)) * 8;                            \
    _Pragma("unroll")                                                             \
    for (int mt = 0; mt < 4; ++mt)                                                \
        af[mt] = *(const short8*)(&As[B][(wm + mt * 16 + fr) * BK + kc_]);        \
} while (0)

#define RD_WG(B, J, H) do {                                                       \
    const int kc_ = (((J) * 4 + quad) ^ (fr & 7)) * 8;                            \
    _Pragma("unroll")                                                             \
    for (int i = 0; i < 2; ++i) {                                                 \
        const int nt = (H) * 2 + i;                                               \
        wf[nt] = *(const short8*)(&Ws[B][(wn + nt * 16 + fr) * BK + kc_]);        \
        gf[nt] = *(const short8*)(&Gs[B][(wn + nt * 16 + fr) * BK + kc_]);        \
    }                                                                             \
} while (0)

    // 16-MFMA cluster for nt-half H (per-acc update order identical to R7/R8)
#define MFMA16(H) do {                                                            \
    __builtin_amdgcn_s_setprio(1);                                                \
    _Pragma("unroll")                                                             \
    for (int mt = 0; mt < 4; ++mt) {                                              \
        _Pragma("unroll")                                                         \
        for (int i = 0; i < 2; ++i) {                                             \
            const int nt = (H) * 2 + i;                                           \
            accB[mt][nt] = __builtin_amdgcn_mfma_f32_16x16x32_bf16(               \
                af[mt], wf[nt], accB[mt][nt], 0, 0, 0);                           \
            accP[mt][nt] = __builtin_amdgcn_mfma_f32_16x16x32_bf16(               \
                af[mt], gf[nt], accP[mt][nt], 0, 0, 0);                           \
        }                                                                         \
    }                                                                             \
    __builtin_amdgcn_s_setprio(0);                                                \
} while (0)

#define BARRIER() __builtin_amdgcn_s_barrier()
#define FENCE()   __builtin_amdgcn_sched_barrier(0)
    // lgkmcnt(0) + sched fence so the MFMA cluster runs wait-free (rule #18)
#define LGKM0() do {                                                              \
    asm volatile("s_waitcnt lgkmcnt(0)" ::: "memory");                            \
    FENCE();                                                                      \
} while (0)

    // One K-tile on buffer B, 4 phases. Phase = (j, nt-half).
    // DOPREF: issue next tile's 8-load burst in phase 0 (target buf B^1 is
    // dead: its last ds_reads completed before tile t-1's final barrier).
    // vmcnt(0) at tile end: loads have ~3.5 phases cover -> no-op-in-time,
    // and the following barrier publishes buf B^1 for the next tile.
#define KTILE(B, DOPREF, K0NEXT) do {                                             \
    if (DOPREF) STAGE(B ^ 1, K0NEXT);                                             \
    RD_A(B, 0); RD_WG(B, 0, 0);                                                   \
    FENCE(); BARRIER(); LGKM0(); MFMA16(0); BARRIER();                            \
    RD_WG(B, 0, 1);                                                               \
    FENCE(); BARRIER(); LGKM0(); MFMA16(1); BARRIER();                            \
    RD_A(B, 1); RD_WG(B, 1, 0);                                                   \
    FENCE(); BARRIER(); LGKM0(); MFMA16(0); BARRIER();                            \
    RD_WG(B, 1, 1);                                                               \
    FENCE(); BARRIER(); LGKM0(); MFMA16(1);                                       \
    asm volatile("s_waitcnt vmcnt(0)" ::: "memory");                              \
    BARRIER();                                                                    \
} while (0)

    // prologue: stage tile 0, publish
    STAGE(0, 0);
    asm volatile("s_waitcnt vmcnt(0)" ::: "memory");
    BARRIER();

#pragma unroll 1
    for (int t2 = 0; t2 < NT - 2; t2 += 2) {
        KTILE(0, 1, (t2 + 1) * BK);
        KTILE(1, 1, (t2 + 2) * BK);
    }
    KTILE(0, 1, (NT - 1) * BK);   // tile 30, prefetch tile 31
    KTILE(1, 0, 0);               // tile 31, no prefetch

#undef STAGE
#undef RD_A
#undef RD_WG
#undef MFMA16
#undef KTILE
#undef LGKM0
#undef FENCE
#undef BARRIER

    // --- epilogue: out = base + bias[n] - lr[m]*(pert + bgrad[n]) ---
    // C/D layout: col = lane&15, row = quad*4 + reg  (verified R2-R8)
    const int col = fr;
    const int gmb = by * BM + wm;
    const int gnb = bx * BN + wn;

    float lrv[4][4];
#pragma unroll
    for (int mt = 0; mt < 4; ++mt)
#pragma unroll
        for (int i = 0; i < 4; ++i)
            lrv[mt][i] = lr[gmb + mt * 16 + quad * 4 + i];

#pragma unroll
    for (int nt = 0; nt < 4; ++nt) {
        const int gn = gnb + nt * 16 + col;
        const float bn = bias[gn];
        const float bg = bgrad[gn];
#pragma unroll
        for (int mt = 0; mt < 4; ++mt) {
#pragma unroll
            for (int i = 0; i < 4; ++i) {
                const int gm = gmb + mt * 16 + quad * 4 + i;
                float v = accB[mt][nt][i] + bn - lrv[mt][i] * (accP[mt][nt][i] + bg);
                __builtin_nontemporal_store(v, out + (size_t)gm * Ndim + gn);
            }
        }
    }
}

extern "C" void kernel_launch(void* const* d_in, const int* in_sizes, int n_in,
                              void* d_out, int out_size, void* d_ws, size_t ws_size,
                              hipStream_t stream) {
    const float* x     = (const float*)d_in[0];  // [4096, 2048]
    const float* W     = (const float*)d_in[1];  // [2048, 2048]
    const float* bias  = (const float*)d_in[2];  // [2048]
    const float* G     = (const float*)d_in[3];  // [2048, 2048]
    const float* bgrad = (const float*)d_in[4];  // [2048]
    const float* lr    = (const float*)d_in[5];  // [4096]
    float* out = (float*)d_out;

    const int nX = 4096 * 2048;
    const int nW = 2048 * 2048;

    ushort_t* xb = (ushort_t*)d_ws;
    ushort_t* wb = xb + nX;
    ushort_t* gb = wb + nW;

    const int uX = nX / 8, uW = nW / 8;
    const int totalU = uX + 2 * uW;               // 2,097,152
    cvt_all_kernel<<<totalU / 256, 256, 0, stream>>>(x, W, G, xb, wb, gb, uX, uW);

    dim3 grid(16, 16);   // N tiles x M tiles = 256 blocks = 1/CU
    fused_gemm_kernel<<<grid, 512, 0, stream>>>(xb, wb, gb, bias, bgrad, lr, out);
}